// Round 6
// baseline (775.629 us; speedup 1.0000x reference)
//
#include <hip/hip_runtime.h>
#include <hip/hip_bf16.h>

#define D 128

typedef unsigned short u16;
typedef unsigned int   u32;
typedef unsigned long long u64;
typedef short bf16x8 __attribute__((ext_vector_type(8)));
typedef float f32x4  __attribute__((ext_vector_type(4)));

__device__ __forceinline__ float bf2f(u16 u) {
    union { u32 i; float f; } v; v.i = ((u32)u) << 16; return v.f;
}
__device__ __forceinline__ float bflo(u32 p) {
    union { u32 i; float f; } v; v.i = p << 16; return v.f;
}
__device__ __forceinline__ float bfhi(u32 p) {
    union { u32 i; float f; } v; v.i = p & 0xffff0000u; return v.f;
}
__device__ __forceinline__ u16 f2bf(float f) {
    union { float f; u32 i; } v; v.f = f;
    return (u16)((v.i + 0x7fffu + ((v.i >> 16) & 1u)) >> 16);
}
__device__ __forceinline__ float ldf(const void* p, long i, int isb) {
    return isb ? bf2f(((const u16*)p)[i]) : ((const float*)p)[i];
}

__device__ __forceinline__ float sigm(float x) { return 1.0f / (1.0f + __expf(-x)); }
__device__ __forceinline__ float tanh_fast(float x) {
    float a = fabsf(x);
    float t = __expf(-2.0f * a);
    float r = (1.0f - t) / (1.0f + t);
    return copysignf(r, x);
}

__global__ void DRlocal_net_79173427135059_kernel() {}

// K-1: runtime dtype detection. flag[0]=inputs-are-bf16, flag[1]=node_id-is-int64.
__global__ __launch_bounds__(64) void k_detect(const void* ent, const void* nid, int* flag) {
    int lane = threadIdx.x;
    float a = fabsf(bf2f(((const u16*)ent)[lane]));
    bool sane = (a >= 9.765625e-4f && a <= 64.0f);
    u64 m = __ballot(sane);
    u32 w = ((const u32*)nid)[lane];
    bool oddzero = ((lane & 1) == 0) || (w == 0u);
    u64 m2 = __ballot(oddzero);
    if (lane == 0) {
        flag[0] = (__popcll(m) >= 48) ? 1 : 0;
        flag[1] = (m2 == ~0ull) ? 1 : 0;
    }
}

// K0: WTb[j][k] = bf16(W[k][j]); GRU weights -> bf16 as-is; biases -> f32.
__global__ __launch_bounds__(256) void k_prep(
    const void* __restrict__ w_ih, const void* __restrict__ w_hh,
    const void* __restrict__ b_ih, const void* __restrict__ b_hh,
    const void* __restrict__ W, const int* __restrict__ flag,
    u16* __restrict__ WTb, u16* __restrict__ Wihb, u16* __restrict__ Whhb,
    float* __restrict__ bif, float* __restrict__ bhf)
{
    int isb = flag[0];
    int t = blockIdx.x * 256 + threadIdx.x;
    if (t < 16384) {
        int k = t >> 7, j = t & 127;
        u16 v = isb ? ((const u16*)W)[t] : f2bf(((const float*)W)[t]);
        WTb[j * 128 + k] = v;
        return;
    }
    int u = t - 16384;
    if (u < 98304) { Wihb[u] = isb ? ((const u16*)w_ih)[u] : f2bf(((const float*)w_ih)[u]); return; }
    int v = u - 98304;
    if (v < 49152) { Whhb[v] = isb ? ((const u16*)w_hh)[v] : f2bf(((const float*)w_hh)[v]); return; }
    int b = v - 49152;
    if (b < 384) { bif[b] = ldf(b_ih, b, isb); return; }
    int c = b - 384;
    if (c < 384) { bhf[c] = ldf(b_hh, c, isb); return; }
}

__global__ __launch_bounds__(256) void k_zero(int* __restrict__ cnt, int n) {
    int t = blockIdx.x * 256 + threadIdx.x;
    if (t < n) cnt[t] = 0;
}

// K1: hW = gather(ent, node_id) @ W via MFMA. 64 nodes/block, wave = one 16-row m-tile.
__global__ __launch_bounds__(256) void k_gmm_mfma(
    const void* __restrict__ ent, const void* __restrict__ node_id,
    const u16* __restrict__ WTb, u16* __restrict__ hW,
    const int* __restrict__ flag, int N)
{
    int isb = flag[0], i64 = flag[1];
    int tid = threadIdx.x;
    int wave = tid >> 6, lane = tid & 63;
    int qm = lane >> 4, qr = lane & 15;
    int row0 = blockIdx.x * 64 + wave * 16;

    int rowA = row0 + qr; if (rowA >= N) rowA = N - 1;
    long nid = i64 ? (long)((const long long*)node_id)[rowA]
                   : (long)((const int*)node_id)[rowA];

    bf16x8 a[4];
    if (isb) {
        const u16* ep = (const u16*)ent + nid * 128 + qm * 8;
        #pragma unroll
        for (int s = 0; s < 4; ++s) a[s] = *(const bf16x8*)(ep + s * 32);
    } else {
        const float* ep = (const float*)ent + nid * 128 + qm * 8;
        #pragma unroll
        for (int s = 0; s < 4; ++s) {
            float4 f0 = *(const float4*)(ep + s * 32);
            float4 f1 = *(const float4*)(ep + s * 32 + 4);
            bf16x8 t;
            t[0] = (short)f2bf(f0.x); t[1] = (short)f2bf(f0.y);
            t[2] = (short)f2bf(f0.z); t[3] = (short)f2bf(f0.w);
            t[4] = (short)f2bf(f1.x); t[5] = (short)f2bf(f1.y);
            t[6] = (short)f2bf(f1.z); t[7] = (short)f2bf(f1.w);
            a[s] = t;
        }
    }

    int r0 = row0 + qm * 4;
    #pragma unroll
    for (int f = 0; f < 8; ++f) {
        f32x4 acc = {0.f, 0.f, 0.f, 0.f};
        const u16* wp = WTb + (size_t)(f * 16 + qr) * 128 + qm * 8;
        #pragma unroll
        for (int s = 0; s < 4; ++s) {
            bf16x8 b = *(const bf16x8*)(wp + s * 32);
            acc = __builtin_amdgcn_mfma_f32_16x16x32_bf16(a[s], b, acc, 0, 0, 0);
        }
        int col = f * 16 + qr;
        #pragma unroll
        for (int r = 0; r < 4; ++r) {
            int row = r0 + r;
            if (row < N) hW[(size_t)row * 128 + col] = f2bf(acc[r]);
        }
    }
}

// ---- CSR build ----
__global__ __launch_bounds__(256) void k_hist(
    const int* __restrict__ edst, int* __restrict__ cnt, int E)
{
    int e = blockIdx.x * 256 + threadIdx.x;
    if (e < E) atomicAdd(&cnt[edst[e]], 1);
}

__global__ __launch_bounds__(256) void k_scan1(
    const int* __restrict__ cnt, int* __restrict__ rowstart,
    int* __restrict__ part, int N)
{
    __shared__ int ssum[256];
    int b = blockIdx.x, t = threadIdx.x;
    int base = b * 1024 + t * 4;
    int v[4]; int s = 0;
    #pragma unroll
    for (int i = 0; i < 4; ++i) {
        int idx = base + i;
        v[i] = (idx < N) ? cnt[idx] : 0;
        s += v[i];
    }
    ssum[t] = s;
    __syncthreads();
    #pragma unroll
    for (int off = 1; off < 256; off <<= 1) {
        int x = (t >= off) ? ssum[t - off] : 0;
        __syncthreads();
        ssum[t] += x;
        __syncthreads();
    }
    int run = ssum[t] - s;
    #pragma unroll
    for (int i = 0; i < 4; ++i) {
        int idx = base + i;
        if (idx < N) rowstart[idx] = run;
        run += v[i];
    }
    if (t == 255) part[b] = ssum[255];
}

__global__ __launch_bounds__(64) void k_scan2(
    int* __restrict__ part, int* __restrict__ rowstart, int nb, int N)
{
    if (threadIdx.x == 0) {
        int run = 0;
        for (int b = 0; b < nb; ++b) { int x = part[b]; part[b] = run; run += x; }
        rowstart[N] = run;
    }
}

__global__ __launch_bounds__(256) void k_scan3(
    int* __restrict__ rowstart, const int* __restrict__ part,
    int* __restrict__ cursor, int N)
{
    int t = blockIdx.x * 256 + threadIdx.x;
    if (t < N) {
        int r = rowstart[t] + part[t >> 10];
        rowstart[t] = r;
        cursor[t] = r;
    }
}

__global__ __launch_bounds__(256) void k_fill(
    const int* __restrict__ esrc, const int* __restrict__ edst,
    int* __restrict__ cursor, int* __restrict__ sorted_src, int E)
{
    int e = blockIdx.x * 256 + threadIdx.x;
    if (e < E) {
        int d = edst[e];
        int pos = atomicAdd(&cursor[d], 1);
        sorted_src[pos] = esrc[e];
    }
}

// K3: segment sum -> X[:,0:128] = bf16(agg*out_norm); also X[:,128:256] = e_r_bias.
__global__ __launch_bounds__(256) void k_seg(
    const u16* __restrict__ hW, const int* __restrict__ rowstart,
    const int* __restrict__ sorted_src, const void* __restrict__ onorm,
    const void* __restrict__ bias, u16* __restrict__ X,
    const int* __restrict__ flag, int N)
{
    int isb = flag[0];
    int tid = threadIdx.x;
    int node = blockIdx.x * 4 + (tid >> 6);
    int lane = tid & 63;
    if (node >= N) return;
    int beg = rowstart[node], end = rowstart[node + 1];
    const u32* hw2 = (const u32*)hW;
    float a0 = 0.f, a1 = 0.f;
    int e = beg;
    for (; e + 4 <= end; e += 4) {
        int s0 = sorted_src[e], s1 = sorted_src[e + 1];
        int s2 = sorted_src[e + 2], s3 = sorted_src[e + 3];
        u32 v0 = hw2[(size_t)s0 * 64 + lane];
        u32 v1 = hw2[(size_t)s1 * 64 + lane];
        u32 v2 = hw2[(size_t)s2 * 64 + lane];
        u32 v3 = hw2[(size_t)s3 * 64 + lane];
        a0 += bflo(v0) + bflo(v1) + bflo(v2) + bflo(v3);
        a1 += bfhi(v0) + bfhi(v1) + bfhi(v2) + bfhi(v3);
    }
    for (; e < end; ++e) {
        u32 v = hw2[(size_t)sorted_src[e] * 64 + lane];
        a0 += bflo(v); a1 += bfhi(v);
    }
    float on = ldf(onorm, node, isb);
    u32 p = ((u32)f2bf(a1 * on) << 16) | (u32)f2bf(a0 * on);
    ((u32*)X)[(size_t)node * 128 + lane] = p;
    u32 pb;
    if (isb) pb = ((const u32*)bias)[(size_t)node * 64 + lane];
    else {
        const float* bp = (const float*)bias + (size_t)node * 128 + lane * 2;
        pb = ((u32)f2bf(bp[1]) << 16) | (u32)f2bf(bp[0]);
    }
    ((u32*)X)[(size_t)node * 128 + 64 + lane] = pb;
}

// K4 v2: MFMA GRU with register-resident gate combine.
// Wave w owns cols {g*128 + w*32 + c*16 + qr} for gates g=r,z,n — so for a fixed
// (row, j) the three gate accumulators sit in the SAME lane, same reg. No LDS
// gate exchange; only a 512B per-row sum-of-squares tile for the L2 norm.
__global__ __launch_bounds__(256) void k_gru_mfma(
    const u16* __restrict__ X, const u16* __restrict__ Wih,
    const u16* __restrict__ Whh, const float* __restrict__ bif,
    const float* __restrict__ bhf, void* __restrict__ out,
    const int* __restrict__ flag, int N)
{
    __shared__ float ssp[32][4];   // [row-in-block][wave] partial sum-of-squares
    int isb = flag[0];
    int tid = threadIdx.x;
    int wave = tid >> 6, lane = tid & 63;
    int qm = lane >> 4, qr = lane & 15;
    int row0 = blockIdx.x * 32;
    int cb = wave * 32;            // this wave's column base within [0,128)

    float h0v[2][2][4];            // [ms][c][reg]

    #pragma unroll
    for (int ms = 0; ms < 2; ++ms) {
        // A-frags for this 16-row tile, k = s*32 + qm*8 + j
        bf16x8 a[8];
        const u16* xb = X + (size_t)(row0 + ms * 16 + qr) * 256 + qm * 8;
        #pragma unroll
        for (int s = 0; s < 8; ++s) a[s] = *(const bf16x8*)(xb + s * 32);

        f32x4 accA[6], accB[6];    // f = g*2 + c
        f32x4 zz = {0.f, 0.f, 0.f, 0.f};
        #pragma unroll
        for (int f = 0; f < 6; ++f) { accA[f] = zz; accB[f] = zz; }

        #pragma unroll
        for (int f = 0; f < 6; ++f) {
            int g = f >> 1, c = f & 1;
            int col = g * 128 + cb + c * 16 + qr;
            const u16* wpA = Wih + (size_t)col * 256 + qm * 8;
            #pragma unroll
            for (int s = 0; s < 8; ++s) {
                bf16x8 b = *(const bf16x8*)(wpA + s * 32);
                accA[f] = __builtin_amdgcn_mfma_f32_16x16x32_bf16(a[s], b, accA[f], 0, 0, 0);
            }
            const u16* wpB = Whh + (size_t)col * 128 + qm * 8;
            #pragma unroll
            for (int s = 0; s < 4; ++s) {
                bf16x8 b = *(const bf16x8*)(wpB + s * 32);
                accB[f] = __builtin_amdgcn_mfma_f32_16x16x32_bf16(a[4 + s], b, accB[f], 0, 0, 0);
            }
        }

        // gate combine in registers
        #pragma unroll
        for (int c = 0; c < 2; ++c) {
            int j = cb + c * 16 + qr;
            float bir = bif[j],       bhr = bhf[j];
            float biz = bif[128 + j], bhz = bhf[128 + j];
            float bin = bif[256 + j], bhn = bhf[256 + j];
            #pragma unroll
            for (int r = 0; r < 4; ++r) {
                int row = row0 + ms * 16 + qm * 4 + r;
                float rg = sigm((accA[c][r] + bir) + (accB[c][r] + bhr));
                float zg = sigm((accA[2 + c][r] + biz) + (accB[2 + c][r] + bhz));
                float ng = tanh_fast((accA[4 + c][r] + bin) + rg * (accB[4 + c][r] + bhn));
                float h  = bf2f(X[(size_t)row * 256 + 128 + j]);
                float h0 = (1.f - zg) * ng + zg * h;
                h0v[ms][c][r] = fmaxf(h0, 0.f);
            }
        }

        // per-row partial sum of squares over this wave's 32 cols
        #pragma unroll
        for (int r = 0; r < 4; ++r) {
            float ss = h0v[ms][0][r] * h0v[ms][0][r] + h0v[ms][1][r] * h0v[ms][1][r];
            ss += __shfl_xor(ss, 1);
            ss += __shfl_xor(ss, 2);
            ss += __shfl_xor(ss, 4);
            ss += __shfl_xor(ss, 8);
            if (qr == 0) ssp[ms * 16 + qm * 4 + r][wave] = ss;
        }
    }
    __syncthreads();

    // finalize: inv-norm per row (broadcast LDS reads), scale, store
    #pragma unroll
    for (int ms = 0; ms < 2; ++ms) {
        #pragma unroll
        for (int r = 0; r < 4; ++r) {
            int rl = ms * 16 + qm * 4 + r;
            int gn = row0 + rl;
            float ssq = ssp[rl][0] + ssp[rl][1] + ssp[rl][2] + ssp[rl][3];
            float inv = 1.f / fmaxf(sqrtf(ssq), 1e-12f);
            if (gn < N) {
                #pragma unroll
                for (int c = 0; c < 2; ++c) {
                    int j = cb + c * 16 + qr;
                    float v = h0v[ms][c][r] * inv;
                    if (isb) ((u16*)out)[(size_t)gn * 128 + j] = f2bf(v);
                    else     ((float*)out)[(size_t)gn * 128 + j] = v;
                }
            }
        }
    }
}

extern "C" void kernel_launch(void* const* d_in, const int* in_sizes, int n_in,
                              void* d_out, int out_size, void* d_ws, size_t ws_size,
                              hipStream_t stream) {
    const void* ent     = d_in[0];
    const void* bias    = d_in[2];
    const void* onorm   = d_in[3];
    const void* W       = d_in[4];
    const void* w_ih    = d_in[5];
    const void* w_hh    = d_in[6];
    const void* b_ih    = d_in[7];
    const void* b_hh    = d_in[8];
    const void* node_id = d_in[9];
    const int*  esrc    = (const int*)d_in[10];
    const int*  edst    = (const int*)d_in[11];

    int N = in_sizes[2] / D;     // 100000
    int E = in_sizes[10];        // 1600000
    int Npad = ((N + 31) / 32) * 32;

    char* ws = (char*)d_ws;
    size_t o = 0;
    int*   flag = (int*)(ws + o);   o += 64;
    u16*   WTb  = (u16*)(ws + o);   o += 16384u * 2;
    u16*   Wihb = (u16*)(ws + o);   o += 98304u * 2;
    u16*   Whhb = (u16*)(ws + o);   o += 49152u * 2;
    float* bif  = (float*)(ws + o); o += 2048;
    float* bhf  = (float*)(ws + o); o += 2048;
    u16*   X    = (u16*)(ws + o);   o += (size_t)Npad * 256 * 2;
    u16*   hW   = (u16*)(ws + o);   o += (size_t)N * D * 2;
    int*   cnt  = (int*)(ws + o);   o += (size_t)N * 4;
    int*   rowstart = (int*)(ws + o); o += ((size_t)N + 16) * 4;
    int*   part = (int*)(ws + o);   o += 4096;
    int*   sorted_src = (int*)(ws + o); o += (size_t)E * 4;
    int*   cursor = cnt;

    int nb = (N + 1023) / 1024;

    k_detect<<<1, 64, 0, stream>>>(ent, node_id, flag);
    k_prep<<<643, 256, 0, stream>>>(w_ih, w_hh, b_ih, b_hh, W, flag,
                                    WTb, Wihb, Whhb, bif, bhf);
    k_zero<<<(N + 255) / 256, 256, 0, stream>>>(cnt, N);
    k_gmm_mfma<<<(N + 63) / 64, 256, 0, stream>>>(ent, node_id, WTb, hW, flag, N);
    k_hist<<<(E + 255) / 256, 256, 0, stream>>>(edst, cnt, E);
    k_scan1<<<nb, 256, 0, stream>>>(cnt, rowstart, part, N);
    k_scan2<<<1, 64, 0, stream>>>(part, rowstart, nb, N);
    k_scan3<<<(N + 255) / 256, 256, 0, stream>>>(rowstart, part, cursor, N);
    k_fill<<<(E + 255) / 256, 256, 0, stream>>>(esrc, edst, cursor, sorted_src, E);
    k_seg<<<(N + 3) / 4, 256, 0, stream>>>(hW, rowstart, sorted_src, onorm, bias, X, flag, N);
    k_gru_mfma<<<Npad / 32, 256, 0, stream>>>(X, Wihb, Whhb, bif, bhf, d_out, flag, N);
}